// Round 2
// baseline (3794.340 us; speedup 1.0000x reference)
//
#include <hip/hip_runtime.h>
#include <hip/hip_bf16.h>
#include <math.h>

#define L_TOK 16384
#define D_INP 256
#define D_MOD 768
#define D_FF  1536
#define N_LAYER 8
#define S_T 64
#define S_G 256
#define EPSV 1e-5f

typedef short bf16x8 __attribute__((ext_vector_type(8)));
typedef float f32x4 __attribute__((ext_vector_type(4)));
typedef __hip_bfloat16 bf16;

__device__ __forceinline__ float fsigmoid(float z) { return 1.0f / (1.0f + __expf(-z)); }

// ---------------- elementwise f32 -> bf16 ----------------
__global__ void k_f32_to_bf16(const float* __restrict__ src, bf16* __restrict__ dst, int n) {
  int i = blockIdx.x * blockDim.x + threadIdx.x;
  if (i < n) dst[i] = __float2bfloat16(src[i]);
}

// ------- transpose+convert: src [R,C] f32 -> dst [C,R] bf16 -------
// R, C multiples of 32. block (32,8), grid (C/32, R/32)
__global__ void k_transpose_bf16(const float* __restrict__ src, bf16* __restrict__ dst,
                                 int R, int C) {
  __shared__ float tile[32][33];
  int r0 = blockIdx.y * 32, c0 = blockIdx.x * 32;
  int tx = threadIdx.x, ty = threadIdx.y;
#pragma unroll
  for (int i = ty; i < 32; i += 8)
    tile[i][tx] = src[(size_t)(r0 + i) * C + (c0 + tx)];
  __syncthreads();
#pragma unroll
  for (int i = ty; i < 32; i += 8)
    dst[(size_t)(c0 + i) * R + (r0 + tx)] = __float2bfloat16(tile[tx][i]);
}

// ---------------- LayerNorm over D_MOD=768, one block (256 thr) per row ----------------
template<bool BF16OUT>
__global__ __launch_bounds__(256) void k_layernorm(const float* __restrict__ x,
    const float* __restrict__ g, const float* __restrict__ b, void* __restrict__ outp) {
  int row = blockIdx.x;
  const float* xr = x + (size_t)row * D_MOD;
  int t = threadIdx.x;
  float v[3];
  v[0] = xr[t]; v[1] = xr[t + 256]; v[2] = xr[t + 512];
  float s = v[0] + v[1] + v[2];
  float s2 = v[0]*v[0] + v[1]*v[1] + v[2]*v[2];
#pragma unroll
  for (int o = 32; o >= 1; o >>= 1) {
    s  += __shfl_down(s, o, 64);
    s2 += __shfl_down(s2, o, 64);
  }
  __shared__ float rs[4], rq[4], smu, srv;
  int wv = t >> 6, ln = t & 63;
  if (ln == 0) { rs[wv] = s; rq[wv] = s2; }
  __syncthreads();
  if (t == 0) {
    float ts = rs[0] + rs[1] + rs[2] + rs[3];
    float tq = rq[0] + rq[1] + rq[2] + rq[3];
    float mu = ts / (float)D_MOD;
    float var = tq / (float)D_MOD - mu * mu;
    smu = mu;
    srv = 1.0f / sqrtf(var + EPSV);
  }
  __syncthreads();
  float mu = smu, rv = srv;
#pragma unroll
  for (int j = 0; j < 3; j++) {
    int c = t + j * 256;
    float val = (v[j] - mu) * rv * g[c] + b[c];
    if (BF16OUT) ((bf16*)outp)[(size_t)row * D_MOD + c] = __float2bfloat16(val);
    else         ((float*)outp)[(size_t)row * D_MOD + c] = val;
  }
}

// ---------------- bf16 MFMA GEMM: C = A[M,K] * Bt[N,K]^T + bias, epilogue fused --------
// MODE: 0 = bias only; 1 = sigmoid(bias+); 2 = silu(bias+); 3 = bias + residual
// 64x64 tile, BK=32, 256 threads (4 waves; wave w -> rows 16w..16w+15, all 64 cols)
template<int MODE, bool OUTBF16>
__global__ __launch_bounds__(256) void k_gemm_bt(
    const short* __restrict__ A, const short* __restrict__ Bt,
    const float* __restrict__ bias, const float* __restrict__ res,
    void* __restrict__ outp, int M, int N, int K)
{
  constexpr int LS = 40;  // LDS row stride (elems): 80B rows -> 16B aligned, 2-way banks (free)
  __shared__ short As[64 * LS];
  __shared__ short Bs[64 * LS];
  const int tid = threadIdx.x;
  const int m0 = blockIdx.y * 64;
  const int n0 = blockIdx.x * 64;
  const int lane = tid & 63, wv = tid >> 6;
  const int qd = lane >> 4, l16 = lane & 15;
  const int srow = tid >> 2, sseg = tid & 3;

  const short* ag = A + (size_t)(m0 + srow) * K + sseg * 8;
  const short* bg = Bt + (size_t)(n0 + srow) * K + sseg * 8;
  short* asd = &As[srow * LS + sseg * 8];
  short* bsd = &Bs[srow * LS + sseg * 8];

  f32x4 acc0 = {0.f, 0.f, 0.f, 0.f};
  f32x4 acc1 = acc0, acc2 = acc0, acc3 = acc0;

  const short* afp  = &As[(16 * wv + l16) * LS + qd * 8];
  const short* bfp0 = &Bs[l16 * LS + qd * 8];

  for (int k0 = 0; k0 < K; k0 += 32) {
    uint4 av = *(const uint4*)(ag + k0);
    uint4 bv = *(const uint4*)(bg + k0);
    *(uint4*)asd = av;
    *(uint4*)bsd = bv;
    __syncthreads();
    bf16x8 af = *(const bf16x8*)afp;
    bf16x8 b0 = *(const bf16x8*)(bfp0);
    bf16x8 b1 = *(const bf16x8*)(bfp0 + 16 * LS);
    bf16x8 b2 = *(const bf16x8*)(bfp0 + 32 * LS);
    bf16x8 b3 = *(const bf16x8*)(bfp0 + 48 * LS);
    acc0 = __builtin_amdgcn_mfma_f32_16x16x32_bf16(af, b0, acc0, 0, 0, 0);
    acc1 = __builtin_amdgcn_mfma_f32_16x16x32_bf16(af, b1, acc1, 0, 0, 0);
    acc2 = __builtin_amdgcn_mfma_f32_16x16x32_bf16(af, b2, acc2, 0, 0, 0);
    acc3 = __builtin_amdgcn_mfma_f32_16x16x32_bf16(af, b3, acc3, 0, 0, 0);
    __syncthreads();
  }

  const int gm0 = m0 + 16 * wv + qd * 4;
  f32x4 accs[4] = {acc0, acc1, acc2, acc3};
#pragma unroll
  for (int c = 0; c < 4; c++) {
    int gn = n0 + 16 * c + l16;
    float bc = bias[gn];
#pragma unroll
    for (int r = 0; r < 4; r++) {
      int gm = gm0 + r;
      float vv = accs[c][r] + bc;
      if (MODE == 1) vv = fsigmoid(vv);
      if (MODE == 2) vv = vv * fsigmoid(vv);
      size_t oidx = (size_t)gm * N + gn;
      if (MODE == 3) vv += res[oidx];
      if (OUTBF16) ((bf16*)outp)[oidx] = __float2bfloat16(vv);
      else         ((float*)outp)[oidx] = vv;
    }
  }
}

// ---------------- chunked linear-recurrence scan (u is bf16) ----------------
// phase A: per-chunk local scan, store chunk-final state. grid S_G x block D_MOD
__global__ void k_scan_a(const bf16* __restrict__ u, const float* __restrict__ dl,
                         float* __restrict__ clast) {
  int d = threadIdx.x;
  int g = blockIdx.x;
  float decay = fsigmoid(dl[d]);
  const bf16* up = u + (size_t)g * S_T * D_MOD + d;
  float s = 0.f;
#pragma unroll 4
  for (int t = 0; t < S_T; t++) s = fmaf(decay, s, __bfloat162float(up[(size_t)t * D_MOD]));
  clast[(size_t)g * D_MOD + d] = s;
}

// phase B: sequential combine across chunks. grid 1 x block D_MOD
__global__ void k_scan_b(const float* __restrict__ clast, const float* __restrict__ dl,
                         float* __restrict__ carry) {
  int d = threadIdx.x;
  float decay = fsigmoid(dl[d]);
  float aT = decay;
#pragma unroll
  for (int i = 0; i < 6; i++) aT *= aT;   // decay^64
  float c = 0.f;
  for (int g = 0; g < S_G; g++) {
    carry[(size_t)g * D_MOD + d] = c;
    c = fmaf(aT, c, clast[(size_t)g * D_MOD + d]);
  }
}

// phase C: re-scan with carry-in, fuse gate multiply, write bf16 in-place over gate buffer
__global__ void k_scan_c(const bf16* __restrict__ u, const float* __restrict__ dl,
                         const float* __restrict__ carry, bf16* __restrict__ gate_s) {
  int d = threadIdx.x;
  int g = blockIdx.x;
  float decay = fsigmoid(dl[d]);
  float s = carry[(size_t)g * D_MOD + d];
  size_t base = (size_t)g * S_T * D_MOD + d;
  for (int t = 0; t < S_T; t++) {
    size_t idx = base + (size_t)t * D_MOD;
    s = fmaf(decay, s, __bfloat162float(u[idx]));
    float gv = __bfloat162float(gate_s[idx]);
    gate_s[idx] = __float2bfloat16(s * gv);
  }
}

extern "C" void kernel_launch(void* const* d_in, const int* in_sizes, int n_in,
                              void* d_out, int out_size, void* d_ws, size_t ws_size,
                              hipStream_t stream) {
  const float* nf     = (const float*)d_in[0];
  const float* W_proj = (const float*)d_in[1];
  const float* b_proj = (const float*)d_in[2];
  const float* ln_s_g = (const float*)d_in[3];
  const float* ln_s_b = (const float*)d_in[4];
  const float* W_in   = (const float*)d_in[5];
  const float* b_in   = (const float*)d_in[6];
  const float* W_gate = (const float*)d_in[7];
  const float* b_gate = (const float*)d_in[8];
  const float* W_out  = (const float*)d_in[9];
  const float* b_out  = (const float*)d_in[10];
  const float* dlogit = (const float*)d_in[11];
  const float* ln_f_g = (const float*)d_in[12];
  const float* ln_f_b = (const float*)d_in[13];
  const float* W_ff1  = (const float*)d_in[14];
  const float* b_ff1  = (const float*)d_in[15];
  const float* W_ff2  = (const float*)d_in[16];
  const float* b_ff2  = (const float*)d_in[17];
  const float* ln_o_g = (const float*)d_in[18];
  const float* ln_o_b = (const float*)d_in[19];
  (void)in_sizes; (void)n_in; (void)ws_size;

  char* ws = (char*)d_ws;
  size_t off = 0;
  auto alloc = [&](size_t bytes) -> char* {
    char* p = ws + off;
    off = (off + bytes + 255) & ~(size_t)255;
    return p;
  };
  // Workspace plan (~136 MB total; round-0's 278 MB likely overflowed ws):
  float* x     = (float*)alloc(sizeof(float) * (size_t)L_TOK * D_MOD);   // 50.3 MB
  bf16*  h     = (bf16*)alloc(2ull * L_TOK * D_MOD);                     // 25.2 MB
  // shared region (50.3 MB): nfb (pre-loop) | u+gate (recurrence) | tb (FF)
  char*  ug    = alloc(2ull * L_TOK * D_FF);
  bf16*  u     = (bf16*)ug;                                // [L,D] bf16, first half
  bf16*  gate  = (bf16*)(ug + 2ull * L_TOK * D_MOD);       // [L,D] bf16, second half
  bf16*  tb    = (bf16*)ug;                                // [L,2D] bf16, whole region
  bf16*  nfb   = (bf16*)ug;                                // [L,DIN] bf16, pre-loop only
  bf16*  WprojT= (bf16*)alloc(2ull * D_INP * D_MOD);       // 0.4 MB
  bf16*  WinT  = (bf16*)alloc(2ull * D_MOD * D_MOD);       // 1.2 MB (per-layer reuse)
  bf16*  WgT   = (bf16*)alloc(2ull * D_MOD * D_MOD);
  bf16*  WoT   = (bf16*)alloc(2ull * D_MOD * D_MOD);
  bf16*  Wff1T = (bf16*)alloc(2ull * D_MOD * D_FF);        // 2.4 MB
  bf16*  Wff2T = (bf16*)alloc(2ull * D_FF * D_MOD);        // 2.4 MB
  float* clast = (float*)alloc(sizeof(float) * (size_t)S_G * D_MOD);    // 0.8 MB
  float* carry = (float*)alloc(sizeof(float) * (size_t)S_G * D_MOD);    // 0.8 MB

  dim3 tb32(32, 8);
  // input conversion + proj weight transpose
  k_f32_to_bf16<<<(L_TOK * D_INP + 255) / 256, 256, 0, stream>>>(nf, nfb, L_TOK * D_INP);
  k_transpose_bf16<<<dim3(D_MOD / 32, D_INP / 32), tb32, 0, stream>>>(W_proj, WprojT, D_INP, D_MOD);

  // x = nf @ W_proj + b_proj  (consumes nfb; frees the ug region)
  k_gemm_bt<0, false><<<dim3(D_MOD / 64, L_TOK / 64), 256, 0, stream>>>(
      (const short*)nfb, (const short*)WprojT, b_proj, nullptr, x, L_TOK, D_MOD, D_INP);

  for (int l = 0; l < N_LAYER; l++) {
    // stage this layer's weights (transpose+convert into reused buffers)
    k_transpose_bf16<<<dim3(D_MOD / 32, D_MOD / 32), tb32, 0, stream>>>(
        W_in + (size_t)l * D_MOD * D_MOD, WinT, D_MOD, D_MOD);
    k_transpose_bf16<<<dim3(D_MOD / 32, D_MOD / 32), tb32, 0, stream>>>(
        W_gate + (size_t)l * D_MOD * D_MOD, WgT, D_MOD, D_MOD);
    k_transpose_bf16<<<dim3(D_MOD / 32, D_MOD / 32), tb32, 0, stream>>>(
        W_out + (size_t)l * D_MOD * D_MOD, WoT, D_MOD, D_MOD);
    k_transpose_bf16<<<dim3(D_FF / 32, D_MOD / 32), tb32, 0, stream>>>(
        W_ff1 + (size_t)l * D_MOD * D_FF, Wff1T, D_MOD, D_FF);
    k_transpose_bf16<<<dim3(D_MOD / 32, D_FF / 32), tb32, 0, stream>>>(
        W_ff2 + (size_t)l * D_FF * D_MOD, Wff2T, D_FF, D_MOD);

    // h = LN_s(x) -> bf16
    k_layernorm<true><<<L_TOK, 256, 0, stream>>>(x, ln_s_g + l * D_MOD, ln_s_b + l * D_MOD, h);
    // u = h @ W_in + b_in (bf16)
    k_gemm_bt<0, true><<<dim3(D_MOD / 64, L_TOK / 64), 256, 0, stream>>>(
        (const short*)h, (const short*)WinT, b_in + l * D_MOD, nullptr, u, L_TOK, D_MOD, D_MOD);
    // gate = sigmoid(h @ W_gate + b_gate) (bf16)
    k_gemm_bt<1, true><<<dim3(D_MOD / 64, L_TOK / 64), 256, 0, stream>>>(
        (const short*)h, (const short*)WgT, b_gate + l * D_MOD, nullptr, gate, L_TOK, D_MOD, D_MOD);
    // chunked scan; s = states*gate -> gate buffer (bf16)
    k_scan_a<<<S_G, D_MOD, 0, stream>>>(u, dlogit + l * D_MOD, clast);
    k_scan_b<<<1, D_MOD, 0, stream>>>(clast, dlogit + l * D_MOD, carry);
    k_scan_c<<<S_G, D_MOD, 0, stream>>>(u, dlogit + l * D_MOD, carry, gate);
    // x = x + s @ W_out + b_out (f32; consumes u+gate, frees ug region)
    k_gemm_bt<3, false><<<dim3(D_MOD / 64, L_TOK / 64), 256, 0, stream>>>(
        (const short*)gate, (const short*)WoT, b_out + l * D_MOD, x, x, L_TOK, D_MOD, D_MOD);
    // hf = LN_f(x) -> bf16 (reuse h)
    k_layernorm<true><<<L_TOK, 256, 0, stream>>>(x, ln_f_g + l * D_MOD, ln_f_b + l * D_MOD, h);
    // tb = silu(hf @ W_ff1 + b_ff1) (bf16, overlays u+gate region)
    k_gemm_bt<2, true><<<dim3(D_FF / 64, L_TOK / 64), 256, 0, stream>>>(
        (const short*)h, (const short*)Wff1T, b_ff1 + l * D_FF, nullptr, tb, L_TOK, D_FF, D_MOD);
    // x = x + tb @ W_ff2 + b_ff2 (f32)
    k_gemm_bt<3, false><<<dim3(D_MOD / 64, L_TOK / 64), 256, 0, stream>>>(
        (const short*)tb, (const short*)Wff2T, b_ff2 + l * D_MOD, x, x, L_TOK, D_MOD, D_FF);
  }

  // out = LN_o(x) (f32)
  k_layernorm<false><<<L_TOK, 256, 0, stream>>>(x, ln_o_g, ln_o_b, d_out);
}

// Round 3
// 2995.675 us; speedup vs baseline: 1.2666x; 1.2666x over previous
//
#include <hip/hip_runtime.h>
#include <hip/hip_bf16.h>
#include <math.h>
#include <string.h>

#define L_TOK 16384
#define D_INP 256
#define D_MOD 768
#define D_FF  1536
#define N_LAYER 8
#define S_T 64
#define S_G 256
#define EPSV 1e-5f

typedef short bf16x8 __attribute__((ext_vector_type(8)));
typedef float f32x4 __attribute__((ext_vector_type(4)));
typedef __hip_bfloat16 bf16;
typedef unsigned int u32;
typedef unsigned short u16;

__device__ __forceinline__ float fsigmoid(float z) { return 1.0f / (1.0f + __expf(-z)); }

__device__ __forceinline__ u16 f2bf(float f) {
  __hip_bfloat16 h = __float2bfloat16(f);
  u16 r; memcpy(&r, &h, 2); return r;
}
__device__ __forceinline__ float bf2f(u16 v) {
  u32 x = ((u32)v) << 16; float f; memcpy(&f, &x, 4); return f;
}

// async global->LDS, 16B per lane. LDS dest = (wave-uniform base) + lane*16.
__device__ __forceinline__ void glds16(const short* g, short* l) {
  __builtin_amdgcn_global_load_lds(
      (const __attribute__((address_space(1))) unsigned int*)(g),
      (__attribute__((address_space(3))) unsigned int*)(l), 16, 0, 0);
}

// ---------------- f32 -> bf16, vectorized (n % 4 == 0) ----------------
__global__ void k_f32_to_bf16v(const float4* __restrict__ src, ushort4* __restrict__ dst, int n4) {
  int i = blockIdx.x * blockDim.x + threadIdx.x;
  if (i < n4) {
    float4 v = src[i];
    ushort4 o; o.x = f2bf(v.x); o.y = f2bf(v.y); o.z = f2bf(v.z); o.w = f2bf(v.w);
    dst[i] = o;
  }
}

// ------- transpose+convert: src [NMAT,R,C] f32 -> dst [NMAT,C,R] bf16 -------
// R, C multiples of 32. block (32,8), grid (C/32, R/32, NMAT)
__global__ void k_transpose_bf16(const float* __restrict__ src, bf16* __restrict__ dst,
                                 int R, int C) {
  __shared__ float tile[32][33];
  size_t mo = (size_t)blockIdx.z * R * C;
  int r0 = blockIdx.y * 32, c0 = blockIdx.x * 32;
  int tx = threadIdx.x, ty = threadIdx.y;
#pragma unroll
  for (int i = ty; i < 32; i += 8)
    tile[i][tx] = src[mo + (size_t)(r0 + i) * C + (c0 + tx)];
  __syncthreads();
#pragma unroll
  for (int i = ty; i < 32; i += 8)
    dst[mo + (size_t)(c0 + i) * R + (r0 + tx)] = __float2bfloat16(tile[tx][i]);
}

// ---------------- LayerNorm over D_MOD=768: 4 waves/block, one wave per row ----------
// float4 loads, shuffle-only butterfly reduction (no LDS, no barrier).
template<bool BF16OUT>
__global__ __launch_bounds__(256) void k_layernorm(const float* __restrict__ x,
    const float* __restrict__ g, const float* __restrict__ b, void* __restrict__ outp) {
  int wv = threadIdx.x >> 6, lane = threadIdx.x & 63;
  int row = blockIdx.x * 4 + wv;
  const float4* xr = (const float4*)(x + (size_t)row * D_MOD);
  float4 v[3];
  float s = 0.f, s2 = 0.f;
#pragma unroll
  for (int j = 0; j < 3; j++) {
    v[j] = xr[j * 64 + lane];
    s  += v[j].x + v[j].y + v[j].z + v[j].w;
    s2 += v[j].x*v[j].x + v[j].y*v[j].y + v[j].z*v[j].z + v[j].w*v[j].w;
  }
#pragma unroll
  for (int o = 32; o >= 1; o >>= 1) {
    s  += __shfl_xor(s, o, 64);
    s2 += __shfl_xor(s2, o, 64);
  }
  float mu = s * (1.0f / (float)D_MOD);
  float var = s2 * (1.0f / (float)D_MOD) - mu * mu;
  float rv = 1.0f / sqrtf(var + EPSV);
  const float4* g4 = (const float4*)g;
  const float4* b4 = (const float4*)b;
#pragma unroll
  for (int j = 0; j < 3; j++) {
    int f = j * 64 + lane;
    float4 gg = g4[f], bb = b4[f], ov;
    ov.x = (v[j].x - mu) * rv * gg.x + bb.x;
    ov.y = (v[j].y - mu) * rv * gg.y + bb.y;
    ov.z = (v[j].z - mu) * rv * gg.z + bb.z;
    ov.w = (v[j].w - mu) * rv * gg.w + bb.w;
    if (BF16OUT) {
      ushort4 o4; o4.x = f2bf(ov.x); o4.y = f2bf(ov.y); o4.z = f2bf(ov.z); o4.w = f2bf(ov.w);
      ((ushort4*)outp)[(size_t)row * 192 + f] = o4;
    } else {
      ((float4*)outp)[(size_t)row * 192 + f] = ov;
    }
  }
}

// ---------------- bf16 MFMA GEMM, m97 structure ----------------
// C[M,N] = A[M,K] * Bt[N,K]^T (+bias, epilogue fused). 128x128 tile, BK=32,
// 256 thr (4 waves as 2x2 of 64x64), global_load_lds w=16 staging,
// XOR-swizzled LDS chunks so ds_read_b128 is <=2-way bank aliased (free).
// MODE: 0 bias; 1 sigmoid; 2 silu; 3 bias+residual
template<int MODE, bool OUTBF16>
__global__ __launch_bounds__(256) void k_gemm128(
    const short* __restrict__ A, const short* __restrict__ Bt,
    const float* __restrict__ bias, const float* __restrict__ res,
    void* __restrict__ outp, int N, int K)
{
  __shared__ short As[128 * 32];
  __shared__ short Bs[128 * 32];
  const int tid = threadIdx.x;
  const int lane = tid & 63, w = tid >> 6;
  const int wr = w >> 1, wc = w & 1;
  const int l16 = lane & 15, qd = lane >> 4;
  const int m0 = blockIdx.y * 128, n0 = blockIdx.x * 128;

  // staging: wave w covers tile rows w*32..w*32+31 (2 glds per matrix)
  const int sr = lane >> 2, sc = lane & 3;
  const int ar = w * 32 + sr;
  const int acx = sc ^ ((ar >> 1) & 3);          // same swizzle for ar and ar+16
  const short* ag0 = A  + (size_t)(m0 + ar) * K + acx * 8;
  const short* ag1 = ag0 + (size_t)16 * K;
  const short* bg0 = Bt + (size_t)(n0 + ar) * K + acx * 8;
  const short* bg1 = bg0 + (size_t)16 * K;
  short* asl0 = &As[w * 1024];  short* asl1 = asl0 + 512;   // wave-uniform LDS bases
  short* bsl0 = &Bs[w * 1024];  short* bsl1 = bsl0 + 512;

  // fragment read: logical chunk qd of row r lives at physical chunk qd^((r>>1)&3)
  const int fo = (qd ^ ((l16 >> 1) & 3)) * 8 + l16 * 32;
  const short* afb = &As[wr * 64 * 32 + fo];
  const short* bfb = &Bs[wc * 64 * 32 + fo];

  f32x4 acc[4][4];
#pragma unroll
  for (int i = 0; i < 4; i++)
#pragma unroll
    for (int j = 0; j < 4; j++) acc[i][j] = (f32x4){0.f, 0.f, 0.f, 0.f};

  for (int k0 = 0; k0 < K; k0 += 32) {
    glds16(ag0 + k0, asl0);
    glds16(ag1 + k0, asl1);
    glds16(bg0 + k0, bsl0);
    glds16(bg1 + k0, bsl1);
    __syncthreads();                       // drains vmcnt -> tiles in LDS
    bf16x8 af[4], bf[4];
#pragma unroll
    for (int rt = 0; rt < 4; rt++) af[rt] = *(const bf16x8*)(afb + rt * 16 * 32);
#pragma unroll
    for (int ct = 0; ct < 4; ct++) bf[ct] = *(const bf16x8*)(bfb + ct * 16 * 32);
#pragma unroll
    for (int rt = 0; rt < 4; rt++)
#pragma unroll
      for (int ct = 0; ct < 4; ct++)
        acc[rt][ct] = __builtin_amdgcn_mfma_f32_16x16x32_bf16(af[rt], bf[ct], acc[rt][ct], 0, 0, 0);
    __syncthreads();                       // frags read -> safe to overwrite
  }

  // epilogue: C/D map col=lane&15, row=(lane>>4)*4+reg  [m89/m91-verified]
  const int gmb = m0 + wr * 64 + qd * 4;
  const int gnb = n0 + wc * 64 + l16;
#pragma unroll
  for (int ct = 0; ct < 4; ct++) {
    int gn = gnb + ct * 16;
    float bc = bias[gn];
#pragma unroll
    for (int rt = 0; rt < 4; rt++) {
#pragma unroll
      for (int r = 0; r < 4; r++) {
        int gm = gmb + rt * 16 + r;
        float vv = acc[rt][ct][r] + bc;
        if (MODE == 1) vv = fsigmoid(vv);
        if (MODE == 2) vv = vv * fsigmoid(vv);
        size_t oidx = (size_t)gm * N + gn;
        if (MODE == 3) vv += res[oidx];
        if (OUTBF16) ((bf16*)outp)[oidx] = __float2bfloat16(vv);
        else         ((float*)outp)[oidx] = vv;
      }
    }
  }
}

// ---------------- chunked linear-recurrence scan (u bf16, 4 ch/thread) ----------------
// phase A: per-chunk local scan -> chunk-final state. grid S_G x block 192
__global__ void k_scan_a(const bf16* __restrict__ u, const float* __restrict__ dl,
                         float* __restrict__ clast) {
  int t = threadIdx.x;            // 0..191, 4 channels each
  int g = blockIdx.x;
  int d0 = t * 4;
  float dec[4], s[4] = {0.f, 0.f, 0.f, 0.f};
#pragma unroll
  for (int c = 0; c < 4; c++) dec[c] = fsigmoid(dl[d0 + c]);
  const ushort4* up = (const ushort4*)(u + (size_t)g * S_T * D_MOD) + t;
  for (int tt = 0; tt < S_T; tt++) {
    ushort4 uv = up[(size_t)tt * 192];
    s[0] = fmaf(dec[0], s[0], bf2f(uv.x));
    s[1] = fmaf(dec[1], s[1], bf2f(uv.y));
    s[2] = fmaf(dec[2], s[2], bf2f(uv.z));
    s[3] = fmaf(dec[3], s[3], bf2f(uv.w));
  }
#pragma unroll
  for (int c = 0; c < 4; c++) clast[(size_t)g * D_MOD + d0 + c] = s[c];
}

// phase B: sequential combine across chunks. grid 1 x block D_MOD
__global__ void k_scan_b(const float* __restrict__ clast, const float* __restrict__ dl,
                         float* __restrict__ carry) {
  int d = threadIdx.x;
  float decay = fsigmoid(dl[d]);
  float aT = decay;
#pragma unroll
  for (int i = 0; i < 6; i++) aT *= aT;   // decay^64
  float c = 0.f;
  for (int g = 0; g < S_G; g++) {
    carry[(size_t)g * D_MOD + d] = c;
    c = fmaf(aT, c, clast[(size_t)g * D_MOD + d]);
  }
}

// phase C: re-scan with carry-in, fuse gate multiply, bf16 out over gate buffer
__global__ void k_scan_c(const bf16* __restrict__ u, const float* __restrict__ dl,
                         const float* __restrict__ carry, bf16* __restrict__ gate_s) {
  int t = threadIdx.x;            // 0..191
  int g = blockIdx.x;
  int d0 = t * 4;
  float dec[4], s[4];
#pragma unroll
  for (int c = 0; c < 4; c++) {
    dec[c] = fsigmoid(dl[d0 + c]);
    s[c] = carry[(size_t)g * D_MOD + d0 + c];
  }
  const ushort4* up = (const ushort4*)(u + (size_t)g * S_T * D_MOD) + t;
  ushort4* gp = (ushort4*)(gate_s + (size_t)g * S_T * D_MOD) + t;
  for (int tt = 0; tt < S_T; tt++) {
    ushort4 uv = up[(size_t)tt * 192];
    ushort4 gv = gp[(size_t)tt * 192];
    s[0] = fmaf(dec[0], s[0], bf2f(uv.x));
    s[1] = fmaf(dec[1], s[1], bf2f(uv.y));
    s[2] = fmaf(dec[2], s[2], bf2f(uv.z));
    s[3] = fmaf(dec[3], s[3], bf2f(uv.w));
    ushort4 ov;
    ov.x = f2bf(s[0] * bf2f(gv.x));
    ov.y = f2bf(s[1] * bf2f(gv.y));
    ov.z = f2bf(s[2] * bf2f(gv.z));
    ov.w = f2bf(s[3] * bf2f(gv.w));
    gp[(size_t)tt * 192] = ov;
  }
}

extern "C" void kernel_launch(void* const* d_in, const int* in_sizes, int n_in,
                              void* d_out, int out_size, void* d_ws, size_t ws_size,
                              hipStream_t stream) {
  const float* nf     = (const float*)d_in[0];
  const float* W_proj = (const float*)d_in[1];
  const float* b_proj = (const float*)d_in[2];
  const float* ln_s_g = (const float*)d_in[3];
  const float* ln_s_b = (const float*)d_in[4];
  const float* W_in   = (const float*)d_in[5];
  const float* b_in   = (const float*)d_in[6];
  const float* W_gate = (const float*)d_in[7];
  const float* b_gate = (const float*)d_in[8];
  const float* W_out  = (const float*)d_in[9];
  const float* b_out  = (const float*)d_in[10];
  const float* dlogit = (const float*)d_in[11];
  const float* ln_f_g = (const float*)d_in[12];
  const float* ln_f_b = (const float*)d_in[13];
  const float* W_ff1  = (const float*)d_in[14];
  const float* b_ff1  = (const float*)d_in[15];
  const float* W_ff2  = (const float*)d_in[16];
  const float* b_ff2  = (const float*)d_in[17];
  const float* ln_o_g = (const float*)d_in[18];
  const float* ln_o_b = (const float*)d_in[19];
  (void)in_sizes; (void)n_in;

  char* ws = (char*)d_ws;
  size_t off = 0;
  auto alloc = [&](size_t bytes) -> char* {
    char* p = ws + off;
    off = (off + bytes + 255) & ~(size_t)255;
    return p;
  };
  // big path (~194 MB): all-layer transposed weights staged once.
  // small path (~136 MB, known-good): per-layer staging buffers.
  const bool big = ws_size >= (195ull << 20);
  const size_t wmul = big ? N_LAYER : 1;

  float* x     = (float*)alloc(sizeof(float) * (size_t)L_TOK * D_MOD);   // 50.3 MB
  bf16*  h     = (bf16*)alloc(2ull * L_TOK * D_MOD);                     // 25.2 MB
  // shared region (50.3 MB): nfb (pre-loop) | u+gate (recurrence) | tb (FF)
  char*  ug    = alloc(2ull * L_TOK * D_FF);
  bf16*  u     = (bf16*)ug;
  bf16*  gate  = (bf16*)(ug + 2ull * L_TOK * D_MOD);
  bf16*  tb    = (bf16*)ug;
  bf16*  nfb   = (bf16*)ug;
  bf16*  WprojT= (bf16*)alloc(2ull * D_INP * D_MOD);
  bf16*  WinT  = (bf16*)alloc(2ull * wmul * D_MOD * D_MOD);
  bf16*  WgT   = (bf16*)alloc(2ull * wmul * D_MOD * D_MOD);
  bf16*  WoT   = (bf16*)alloc(2ull * wmul * D_MOD * D_MOD);
  bf16*  Wff1T = (bf16*)alloc(2ull * wmul * D_MOD * D_FF);
  bf16*  Wff2T = (bf16*)alloc(2ull * wmul * D_FF * D_MOD);
  float* clast = (float*)alloc(sizeof(float) * (size_t)S_G * D_MOD);
  float* carry = (float*)alloc(sizeof(float) * (size_t)S_G * D_MOD);

  dim3 tb32(32, 8);
  k_f32_to_bf16v<<<(L_TOK * D_INP / 4 + 255) / 256, 256, 0, stream>>>(
      (const float4*)nf, (ushort4*)nfb, L_TOK * D_INP / 4);
  k_transpose_bf16<<<dim3(D_MOD / 32, D_INP / 32, 1), tb32, 0, stream>>>(W_proj, WprojT, D_INP, D_MOD);
  if (big) {
    k_transpose_bf16<<<dim3(D_MOD / 32, D_MOD / 32, N_LAYER), tb32, 0, stream>>>(W_in,   WinT,  D_MOD, D_MOD);
    k_transpose_bf16<<<dim3(D_MOD / 32, D_MOD / 32, N_LAYER), tb32, 0, stream>>>(W_gate, WgT,   D_MOD, D_MOD);
    k_transpose_bf16<<<dim3(D_MOD / 32, D_MOD / 32, N_LAYER), tb32, 0, stream>>>(W_out,  WoT,   D_MOD, D_MOD);
    k_transpose_bf16<<<dim3(D_FF / 32,  D_MOD / 32, N_LAYER), tb32, 0, stream>>>(W_ff1,  Wff1T, D_MOD, D_FF);
    k_transpose_bf16<<<dim3(D_MOD / 32, D_FF / 32,  N_LAYER), tb32, 0, stream>>>(W_ff2,  Wff2T, D_FF,  D_MOD);
  }

  // x = nf @ W_proj + b_proj (f32)
  k_gemm128<0, false><<<dim3(D_MOD / 128, L_TOK / 128), 256, 0, stream>>>(
      (const short*)nfb, (const short*)WprojT, b_proj, nullptr, x, D_MOD, D_INP);

  for (int l = 0; l < N_LAYER; l++) {
    const bf16 *winT, *wgT, *woT, *wf1T, *wf2T;
    if (big) {
      winT = WinT + (size_t)l * D_MOD * D_MOD;
      wgT  = WgT  + (size_t)l * D_MOD * D_MOD;
      woT  = WoT  + (size_t)l * D_MOD * D_MOD;
      wf1T = Wff1T + (size_t)l * D_MOD * D_FF;
      wf2T = Wff2T + (size_t)l * D_FF * D_MOD;
    } else {
      k_transpose_bf16<<<dim3(D_MOD / 32, D_MOD / 32, 1), tb32, 0, stream>>>(
          W_in + (size_t)l * D_MOD * D_MOD, WinT, D_MOD, D_MOD);
      k_transpose_bf16<<<dim3(D_MOD / 32, D_MOD / 32, 1), tb32, 0, stream>>>(
          W_gate + (size_t)l * D_MOD * D_MOD, WgT, D_MOD, D_MOD);
      k_transpose_bf16<<<dim3(D_MOD / 32, D_MOD / 32, 1), tb32, 0, stream>>>(
          W_out + (size_t)l * D_MOD * D_MOD, WoT, D_MOD, D_MOD);
      k_transpose_bf16<<<dim3(D_FF / 32, D_MOD / 32, 1), tb32, 0, stream>>>(
          W_ff1 + (size_t)l * D_MOD * D_FF, Wff1T, D_MOD, D_FF);
      k_transpose_bf16<<<dim3(D_MOD / 32, D_FF / 32, 1), tb32, 0, stream>>>(
          W_ff2 + (size_t)l * D_FF * D_MOD, Wff2T, D_FF, D_MOD);
      winT = WinT; wgT = WgT; woT = WoT; wf1T = Wff1T; wf2T = Wff2T;
    }

    // h = LN_s(x) -> bf16
    k_layernorm<true><<<L_TOK / 4, 256, 0, stream>>>(x, ln_s_g + l * D_MOD, ln_s_b + l * D_MOD, h);
    // u = h @ W_in + b_in (bf16)
    k_gemm128<0, true><<<dim3(D_MOD / 128, L_TOK / 128), 256, 0, stream>>>(
        (const short*)h, (const short*)winT, b_in + l * D_MOD, nullptr, u, D_MOD, D_MOD);
    // gate = sigmoid(h @ W_gate + b_gate) (bf16)
    k_gemm128<1, true><<<dim3(D_MOD / 128, L_TOK / 128), 256, 0, stream>>>(
        (const short*)h, (const short*)wgT, b_gate + l * D_MOD, nullptr, gate, D_MOD, D_MOD);
    // chunked scan; s = states*gate -> gate buffer (bf16)
    k_scan_a<<<S_G, 192, 0, stream>>>(u, dlogit + l * D_MOD, clast);
    k_scan_b<<<1, D_MOD, 0, stream>>>(clast, dlogit + l * D_MOD, carry);
    k_scan_c<<<S_G, 192, 0, stream>>>(u, dlogit + l * D_MOD, carry, gate);
    // x = x + s @ W_out + b_out (f32)
    k_gemm128<3, false><<<dim3(D_MOD / 128, L_TOK / 128), 256, 0, stream>>>(
        (const short*)gate, (const short*)woT, b_out + l * D_MOD, x, x, D_MOD, D_MOD);
    // hf = LN_f(x) -> bf16 (reuse h)
    k_layernorm<true><<<L_TOK / 4, 256, 0, stream>>>(x, ln_f_g + l * D_MOD, ln_f_b + l * D_MOD, h);
    // tb = silu(hf @ W_ff1 + b_ff1) (bf16)
    k_gemm128<2, true><<<dim3(D_FF / 128, L_TOK / 128), 256, 0, stream>>>(
        (const short*)h, (const short*)wf1T, b_ff1 + l * D_FF, nullptr, tb, D_FF, D_MOD);
    // x = x + tb @ W_ff2 + b_ff2 (f32)
    k_gemm128<3, false><<<dim3(D_MOD / 128, L_TOK / 128), 256, 0, stream>>>(
        (const short*)tb, (const short*)Wff2T + (big ? (size_t)l * D_FF * D_MOD : 0),
        b_ff2 + l * D_MOD, x, x, D_MOD, D_FF);
  }

  // out = LN_o(x) (f32)
  k_layernorm<false><<<L_TOK / 4, 256, 0, stream>>>(x, ln_o_g, ln_o_b, d_out);
}

// Round 4
// 2556.306 us; speedup vs baseline: 1.4843x; 1.1719x over previous
//
#include <hip/hip_runtime.h>
#include <hip/hip_bf16.h>
#include <math.h>
#include <string.h>

#define L_TOK 16384
#define D_INP 256
#define D_MOD 768
#define D_FF  1536
#define N_LAYER 8
#define S_T 64
#define S_G 256
#define EPSV 1e-5f

typedef short bf16x8 __attribute__((ext_vector_type(8)));
typedef float f32x4 __attribute__((ext_vector_type(4)));
typedef __hip_bfloat16 bf16;
typedef unsigned int u32;
typedef unsigned short u16;

__device__ __forceinline__ float fsigmoid(float z) { return 1.0f / (1.0f + __expf(-z)); }

__device__ __forceinline__ u16 f2bf(float f) {
  __hip_bfloat16 h = __float2bfloat16(f);
  u16 r; memcpy(&r, &h, 2); return r;
}
__device__ __forceinline__ float bf2f(u16 v) {
  u32 x = ((u32)v) << 16; float f; memcpy(&f, &x, 4); return f;
}

// async global->LDS, 16B per lane. LDS dest = (wave-uniform base) + lane*16.
__device__ __forceinline__ void glds16(const short* g, short* l) {
  __builtin_amdgcn_global_load_lds(
      (const __attribute__((address_space(1))) unsigned int*)(g),
      (__attribute__((address_space(3))) unsigned int*)(l), 16, 0, 0);
}

// ---------------- f32 -> bf16, vectorized (n % 4 == 0) ----------------
__global__ void k_f32_to_bf16v(const float4* __restrict__ src, ushort4* __restrict__ dst, int n4) {
  int i = blockIdx.x * blockDim.x + threadIdx.x;
  if (i < n4) {
    float4 v = src[i];
    ushort4 o; o.x = f2bf(v.x); o.y = f2bf(v.y); o.z = f2bf(v.z); o.w = f2bf(v.w);
    dst[i] = o;
  }
}

// ------- transpose+convert: src [z][R,C] f32 -> dst [z][C,R] bf16 (strided per z) ----
// R, C multiples of 32. block (32,8), grid (C/32, R/32, NZ)
__global__ void k_transpose_bf16(const float* __restrict__ src, bf16* __restrict__ dst,
                                 int R, int C, size_t sstride, size_t dstride) {
  __shared__ float tile[32][33];
  const float* s = src + (size_t)blockIdx.z * sstride;
  bf16* d = dst + (size_t)blockIdx.z * dstride;
  int r0 = blockIdx.y * 32, c0 = blockIdx.x * 32;
  int tx = threadIdx.x, ty = threadIdx.y;
#pragma unroll
  for (int i = ty; i < 32; i += 8)
    tile[i][tx] = s[(size_t)(r0 + i) * C + (c0 + tx)];
  __syncthreads();
#pragma unroll
  for (int i = ty; i < 32; i += 8)
    d[(size_t)(c0 + i) * R + (r0 + tx)] = __float2bfloat16(tile[tx][i]);
}

// ---------------- LayerNorm over D_MOD=768: 4 waves/block, one wave per row ----------
template<bool BF16OUT>
__global__ __launch_bounds__(256) void k_layernorm(const float* __restrict__ x,
    const float* __restrict__ g, const float* __restrict__ b, void* __restrict__ outp) {
  int wv = threadIdx.x >> 6, lane = threadIdx.x & 63;
  int row = blockIdx.x * 4 + wv;
  const float4* xr = (const float4*)(x + (size_t)row * D_MOD);
  float4 v[3];
  float s = 0.f, s2 = 0.f;
#pragma unroll
  for (int j = 0; j < 3; j++) {
    v[j] = xr[j * 64 + lane];
    s  += v[j].x + v[j].y + v[j].z + v[j].w;
    s2 += v[j].x*v[j].x + v[j].y*v[j].y + v[j].z*v[j].z + v[j].w*v[j].w;
  }
#pragma unroll
  for (int o = 32; o >= 1; o >>= 1) {
    s  += __shfl_xor(s, o, 64);
    s2 += __shfl_xor(s2, o, 64);
  }
  float mu = s * (1.0f / (float)D_MOD);
  float var = s2 * (1.0f / (float)D_MOD) - mu * mu;
  float rv = 1.0f / sqrtf(var + EPSV);
  const float4* g4 = (const float4*)g;
  const float4* b4 = (const float4*)b;
#pragma unroll
  for (int j = 0; j < 3; j++) {
    int f = j * 64 + lane;
    float4 gg = g4[f], bb = b4[f], ov;
    ov.x = (v[j].x - mu) * rv * gg.x + bb.x;
    ov.y = (v[j].y - mu) * rv * gg.y + bb.y;
    ov.z = (v[j].z - mu) * rv * gg.z + bb.z;
    ov.w = (v[j].w - mu) * rv * gg.w + bb.w;
    if (BF16OUT) {
      ushort4 o4; o4.x = f2bf(ov.x); o4.y = f2bf(ov.y); o4.z = f2bf(ov.z); o4.w = f2bf(ov.w);
      ((ushort4*)outp)[(size_t)row * 192 + f] = o4;
    } else {
      ((float4*)outp)[(size_t)row * 192 + f] = ov;
    }
  }
}

// ---------------- bf16 MFMA GEMM, dbuf + 1-barrier K-loop + XCD band swizzle --------
// C[16384,N] = A[16384,K] * Bt[N,K]^T (+bias, fused epilogue). 128x128 tile, BK=32,
// 256 thr (2x2 waves of 64x64), glds w=16 staging into 2 LDS buffers,
// XOR-swizzled LDS chunks (0 bank conflicts), grid = 1-D 128*ncol blocks.
// MODE: 0 bias; 2 silu; 3 bias+residual; 4 split u|gate (bias / sigmoid+bias2)
template<int MODE, bool OUTBF16>
__global__ __launch_bounds__(256, 4) void k_gemm128(
    const short* __restrict__ A, const short* __restrict__ Bt,
    const float* __restrict__ bias, const float* __restrict__ bias2,
    const float* __restrict__ res, void* __restrict__ outp, void* __restrict__ outp2,
    int N, int K, int ncol)
{
  __shared__ short As[2][128 * 32];
  __shared__ short Bs[2][128 * 32];
  const int tid = threadIdx.x;
  const int lane = tid & 63, w = tid >> 6;
  const int wr = w >> 1, wc = w & 1;
  const int l16 = lane & 15, qd = lane >> 4;

  // XCD band swizzle: xcd = bid&7 owns rows [xcd*16, xcd*16+16), sweeps cols fastest.
  // Per-XCD working set = A band (<=3.2MB) + whole Bt (<=2.4MB) -> fits 4MB L2.
  const int b = blockIdx.x;
  const int xcd = b & 7, t = b >> 3;
  const int m0 = (xcd * 16 + t / ncol) * 128;
  const int n0 = (t % ncol) * 128;

  // staging: wave w covers tile rows w*32..+31; lane = (row_in_8grp)*4... sr=lane>>2 rows, sc chunk
  const int sr = lane >> 2, sc = lane & 3;
  const int ar = w * 32 + sr;
  const int acx = sc ^ ((ar >> 1) & 3);          // XOR chunk swizzle (same for ar, ar+16)
  const short* ag0 = A  + (size_t)(m0 + ar) * K + acx * 8;
  const short* ag1 = ag0 + (size_t)16 * K;
  const short* bg0 = Bt + (size_t)(n0 + ar) * K + acx * 8;
  const short* bg1 = bg0 + (size_t)16 * K;

  // fragment read: logical chunk qd of row r lives at physical chunk qd^((r>>1)&3)
  const int fo = (qd ^ ((l16 >> 1) & 3)) * 8 + l16 * 32;

  f32x4 acc[4][4];
#pragma unroll
  for (int i = 0; i < 4; i++)
#pragma unroll
    for (int j = 0; j < 4; j++) acc[i][j] = (f32x4){0.f, 0.f, 0.f, 0.f};

  // preload tile 0 -> buffer 0
  {
    short* a0 = &As[0][w * 1024];
    glds16(ag0, a0); glds16(ag1, a0 + 512);
    short* b0 = &Bs[0][w * 1024];
    glds16(bg0, b0); glds16(bg1, b0 + 512);
  }
  int p = 0;
  for (int k0 = 0; k0 < K; k0 += 32, p ^= 1) {
    __syncthreads();                 // tile k0 (buf p) resident; drains glds issued last iter
    if (k0 + 32 < K) {               // prefetch tile k0+32 -> buf p^1, overlaps this compute
      short* a0 = &As[p ^ 1][w * 1024];
      glds16(ag0 + k0 + 32, a0); glds16(ag1 + k0 + 32, a0 + 512);
      short* b0 = &Bs[p ^ 1][w * 1024];
      glds16(bg0 + k0 + 32, b0); glds16(bg1 + k0 + 32, b0 + 512);
    }
    const short* afb = &As[p][wr * 2048 + fo];
    const short* bfb = &Bs[p][wc * 2048 + fo];
    bf16x8 af[4], bf[4];
#pragma unroll
    for (int rt = 0; rt < 4; rt++) af[rt] = *(const bf16x8*)(afb + rt * 512);
#pragma unroll
    for (int ct = 0; ct < 4; ct++) bf[ct] = *(const bf16x8*)(bfb + ct * 512);
#pragma unroll
    for (int rt = 0; rt < 4; rt++)
#pragma unroll
      for (int ct = 0; ct < 4; ct++)
        acc[rt][ct] = __builtin_amdgcn_mfma_f32_16x16x32_bf16(af[rt], bf[ct], acc[rt][ct], 0, 0, 0);
  }

  // epilogue: C/D map col=lane&15, row=(lane>>4)*4+reg  [m89/m91-verified]
  // MODE 4: split at N/2 is block-uniform (N/2 % 128 == 0)
  const float* bb = bias;
  void* op = outp;
  int nofs = 0, Nout = N;
  bool sig = false;
  if (MODE == 4) {
    Nout = N >> 1;
    if (n0 >= Nout) { bb = bias2; op = outp2; nofs = Nout; sig = true; }
  }
  const int gmb = m0 + wr * 64 + qd * 4;
  const int gnb = n0 + wc * 64 + l16;
#pragma unroll
  for (int ct = 0; ct < 4; ct++) {
    int gn = gnb + ct * 16;
    float bc = bb[gn - nofs];
#pragma unroll
    for (int rt = 0; rt < 4; rt++) {
#pragma unroll
      for (int r = 0; r < 4; r++) {
        int gm = gmb + rt * 16 + r;
        float vv = acc[rt][ct][r] + bc;
        if (MODE == 2) vv = vv * fsigmoid(vv);
        if (MODE == 4 && sig) vv = fsigmoid(vv);
        size_t oidx = (size_t)gm * Nout + (gn - nofs);
        if (MODE == 3) vv += res[oidx];
        if (OUTBF16) ((bf16*)op)[oidx] = __float2bfloat16(vv);
        else         ((float*)op)[oidx] = vv;
      }
    }
  }
}

// ---------------- chunked linear-recurrence scan (u bf16, 4 ch/thread) ----------------
__global__ void k_scan_a(const bf16* __restrict__ u, const float* __restrict__ dl,
                         float* __restrict__ clast) {
  int t = threadIdx.x;            // 0..191, 4 channels each
  int g = blockIdx.x;
  int d0 = t * 4;
  float dec[4], s[4] = {0.f, 0.f, 0.f, 0.f};
#pragma unroll
  for (int c = 0; c < 4; c++) dec[c] = fsigmoid(dl[d0 + c]);
  const ushort4* up = (const ushort4*)(u + (size_t)g * S_T * D_MOD) + t;
  for (int tt = 0; tt < S_T; tt++) {
    ushort4 uv = up[(size_t)tt * 192];
    s[0] = fmaf(dec[0], s[0], bf2f(uv.x));
    s[1] = fmaf(dec[1], s[1], bf2f(uv.y));
    s[2] = fmaf(dec[2], s[2], bf2f(uv.z));
    s[3] = fmaf(dec[3], s[3], bf2f(uv.w));
  }
#pragma unroll
  for (int c = 0; c < 4; c++) clast[(size_t)g * D_MOD + d0 + c] = s[c];
}

__global__ void k_scan_b(const float* __restrict__ clast, const float* __restrict__ dl,
                         float* __restrict__ carry) {
  int d = threadIdx.x;
  float decay = fsigmoid(dl[d]);
  float aT = decay;
#pragma unroll
  for (int i = 0; i < 6; i++) aT *= aT;   // decay^64
  float c = 0.f;
  for (int g = 0; g < S_G; g++) {
    carry[(size_t)g * D_MOD + d] = c;
    c = fmaf(aT, c, clast[(size_t)g * D_MOD + d]);
  }
}

__global__ void k_scan_c(const bf16* __restrict__ u, const float* __restrict__ dl,
                         const float* __restrict__ carry, bf16* __restrict__ gate_s) {
  int t = threadIdx.x;            // 0..191
  int g = blockIdx.x;
  int d0 = t * 4;
  float dec[4], s[4];
#pragma unroll
  for (int c = 0; c < 4; c++) {
    dec[c] = fsigmoid(dl[d0 + c]);
    s[c] = carry[(size_t)g * D_MOD + d0 + c];
  }
  const ushort4* up = (const ushort4*)(u + (size_t)g * S_T * D_MOD) + t;
  ushort4* gp = (ushort4*)(gate_s + (size_t)g * S_T * D_MOD) + t;
  for (int tt = 0; tt < S_T; tt++) {
    ushort4 uv = up[(size_t)tt * 192];
    ushort4 gv = gp[(size_t)tt * 192];
    s[0] = fmaf(dec[0], s[0], bf2f(uv.x));
    s[1] = fmaf(dec[1], s[1], bf2f(uv.y));
    s[2] = fmaf(dec[2], s[2], bf2f(uv.z));
    s[3] = fmaf(dec[3], s[3], bf2f(uv.w));
    ushort4 ov;
    ov.x = f2bf(s[0] * bf2f(gv.x));
    ov.y = f2bf(s[1] * bf2f(gv.y));
    ov.z = f2bf(s[2] * bf2f(gv.z));
    ov.w = f2bf(s[3] * bf2f(gv.w));
    gp[(size_t)tt * 192] = ov;
  }
}

extern "C" void kernel_launch(void* const* d_in, const int* in_sizes, int n_in,
                              void* d_out, int out_size, void* d_ws, size_t ws_size,
                              hipStream_t stream) {
  const float* nf     = (const float*)d_in[0];
  const float* W_proj = (const float*)d_in[1];
  const float* b_proj = (const float*)d_in[2];
  const float* ln_s_g = (const float*)d_in[3];
  const float* ln_s_b = (const float*)d_in[4];
  const float* W_in   = (const float*)d_in[5];
  const float* b_in   = (const float*)d_in[6];
  const float* W_gate = (const float*)d_in[7];
  const float* b_gate = (const float*)d_in[8];
  const float* W_out  = (const float*)d_in[9];
  const float* b_out  = (const float*)d_in[10];
  const float* dlogit = (const float*)d_in[11];
  const float* ln_f_g = (const float*)d_in[12];
  const float* ln_f_b = (const float*)d_in[13];
  const float* W_ff1  = (const float*)d_in[14];
  const float* b_ff1  = (const float*)d_in[15];
  const float* W_ff2  = (const float*)d_in[16];
  const float* b_ff2  = (const float*)d_in[17];
  const float* ln_o_g = (const float*)d_in[18];
  const float* ln_o_b = (const float*)d_in[19];
  (void)in_sizes; (void)n_in;

  char* ws = (char*)d_ws;
  size_t off = 0;
  auto alloc = [&](size_t bytes) -> char* {
    char* p = ws + off;
    off = (off + bytes + 255) & ~(size_t)255;
    return p;
  };
  // big path (~194 MB): all-layer transposed weights staged once; else per-layer (~136 MB)
  const bool big = ws_size >= (195ull << 20);
  const size_t wmul = big ? N_LAYER : 1;

  float* x     = (float*)alloc(sizeof(float) * (size_t)L_TOK * D_MOD);   // 50.3 MB
  bf16*  h     = (bf16*)alloc(2ull * L_TOK * D_MOD);                     // 25.2 MB
  // shared region (50.3 MB): nfb (pre-loop) | u+gate (recurrence) | tb (FF)
  char*  ug    = alloc(2ull * L_TOK * D_FF);
  bf16*  u     = (bf16*)ug;
  bf16*  gate  = (bf16*)(ug + 2ull * L_TOK * D_MOD);
  bf16*  tb    = (bf16*)ug;
  bf16*  nfb   = (bf16*)ug;
  bf16*  WprojT= (bf16*)alloc(2ull * D_INP * D_MOD);
  bf16*  WigT  = (bf16*)alloc(2ull * wmul * (2 * D_MOD) * D_MOD);  // [W_in^T ; W_gate^T]
  bf16*  WoT   = (bf16*)alloc(2ull * wmul * D_MOD * D_MOD);
  bf16*  Wff1T = (bf16*)alloc(2ull * wmul * D_MOD * D_FF);
  bf16*  Wff2T = (bf16*)alloc(2ull * wmul * D_FF * D_MOD);
  float* clast = (float*)alloc(sizeof(float) * (size_t)S_G * D_MOD);
  float* carry = (float*)alloc(sizeof(float) * (size_t)S_G * D_MOD);

  const size_t DD = (size_t)D_MOD * D_MOD, DF = (size_t)D_MOD * D_FF;
  dim3 tb32(32, 8);
  k_f32_to_bf16v<<<(L_TOK * D_INP / 4 + 255) / 256, 256, 0, stream>>>(
      (const float4*)nf, (ushort4*)nfb, L_TOK * D_INP / 4);
  k_transpose_bf16<<<dim3(D_MOD / 32, D_INP / 32, 1), tb32, 0, stream>>>(
      W_proj, WprojT, D_INP, D_MOD, 0, 0);
  if (big) {
    k_transpose_bf16<<<dim3(D_MOD / 32, D_MOD / 32, N_LAYER), tb32, 0, stream>>>(
        W_in,   WigT,       D_MOD, D_MOD, DD, 2 * DD);
    k_transpose_bf16<<<dim3(D_MOD / 32, D_MOD / 32, N_LAYER), tb32, 0, stream>>>(
        W_gate, WigT + DD,  D_MOD, D_MOD, DD, 2 * DD);
    k_transpose_bf16<<<dim3(D_MOD / 32, D_MOD / 32, N_LAYER), tb32, 0, stream>>>(
        W_out,  WoT,        D_MOD, D_MOD, DD, DD);
    k_transpose_bf16<<<dim3(D_FF / 32,  D_MOD / 32, N_LAYER), tb32, 0, stream>>>(
        W_ff1,  Wff1T,      D_MOD, D_FF,  DF, DF);
    k_transpose_bf16<<<dim3(D_MOD / 32, D_FF / 32,  N_LAYER), tb32, 0, stream>>>(
        W_ff2,  Wff2T,      D_FF,  D_MOD, DF, DF);
  }

  // x = nf @ W_proj + b_proj (f32)
  k_gemm128<0, false><<<128 * 6, 256, 0, stream>>>(
      (const short*)nfb, (const short*)WprojT, b_proj, nullptr, nullptr, x, nullptr,
      D_MOD, D_INP, 6);

  for (int l = 0; l < N_LAYER; l++) {
    const bf16 *wigT, *woT, *wf1T, *wf2T;
    if (big) {
      wigT = WigT  + (size_t)l * 2 * DD;
      woT  = WoT   + (size_t)l * DD;
      wf1T = Wff1T + (size_t)l * DF;
      wf2T = Wff2T + (size_t)l * DF;
    } else {
      k_transpose_bf16<<<dim3(D_MOD / 32, D_MOD / 32, 1), tb32, 0, stream>>>(
          W_in + (size_t)l * DD, WigT, D_MOD, D_MOD, 0, 0);
      k_transpose_bf16<<<dim3(D_MOD / 32, D_MOD / 32, 1), tb32, 0, stream>>>(
          W_gate + (size_t)l * DD, WigT + DD, D_MOD, D_MOD, 0, 0);
      k_transpose_bf16<<<dim3(D_MOD / 32, D_MOD / 32, 1), tb32, 0, stream>>>(
          W_out + (size_t)l * DD, WoT, D_MOD, D_MOD, 0, 0);
      k_transpose_bf16<<<dim3(D_FF / 32, D_MOD / 32, 1), tb32, 0, stream>>>(
          W_ff1 + (size_t)l * DF, Wff1T, D_MOD, D_FF, 0, 0);
      k_transpose_bf16<<<dim3(D_MOD / 32, D_FF / 32, 1), tb32, 0, stream>>>(
          W_ff2 + (size_t)l * DF, Wff2T, D_FF, D_MOD, 0, 0);
      wigT = WigT; woT = WoT; wf1T = Wff1T; wf2T = Wff2T;
    }

    // h = LN_s(x) -> bf16
    k_layernorm<true><<<L_TOK / 4, 256, 0, stream>>>(x, ln_s_g + l * D_MOD, ln_s_b + l * D_MOD, h);
    // fused: u = h@W_in + b_in ; gate = sigmoid(h@W_gate + b_gate)   (both bf16)
    k_gemm128<4, true><<<128 * 12, 256, 0, stream>>>(
        (const short*)h, (const short*)wigT, b_in + l * D_MOD, b_gate + l * D_MOD,
        nullptr, u, gate, 2 * D_MOD, D_MOD, 12);
    // chunked scan; s = states*gate -> gate buffer (bf16)
    k_scan_a<<<S_G, 192, 0, stream>>>(u, dlogit + l * D_MOD, clast);
    k_scan_b<<<1, D_MOD, 0, stream>>>(clast, dlogit + l * D_MOD, carry);
    k_scan_c<<<S_G, 192, 0, stream>>>(u, dlogit + l * D_MOD, carry, gate);
    // x = x + s @ W_out + b_out (f32)
    k_gemm128<3, false><<<128 * 6, 256, 0, stream>>>(
        (const short*)gate, (const short*)woT, b_out + l * D_MOD, nullptr, x, x, nullptr,
        D_MOD, D_MOD, 6);
    // hf = LN_f(x) -> bf16 (reuse h)
    k_layernorm<true><<<L_TOK / 4, 256, 0, stream>>>(x, ln_f_g + l * D_MOD, ln_f_b + l * D_MOD, h);
    // tb = silu(hf @ W_ff1 + b_ff1) (bf16)
    k_gemm128<2, true><<<128 * 12, 256, 0, stream>>>(
        (const short*)h, (const short*)wf1T, b_ff1 + l * D_FF, nullptr, nullptr, tb, nullptr,
        D_FF, D_MOD, 12);
    // x = x + tb @ W_ff2 + b_ff2 (f32)
    k_gemm128<3, false><<<128 * 6, 256, 0, stream>>>(
        (const short*)tb, (const short*)wf2T, b_ff2 + l * D_MOD, nullptr, x, x, nullptr,
        D_MOD, D_FF, 6);
  }

  // out = LN_o(x) (f32)
  k_layernorm<false><<<L_TOK / 4, 256, 0, stream>>>(x, ln_o_g, ln_o_b, d_out);
}